// Round 1
// baseline (2825.871 us; speedup 1.0000x reference)
//
#include <hip/hip_runtime.h>

#define NUSERS 100000
#define NGAMES 50000
#define NEDGES 1000000
// C=64, H=8, D=8, NEG_SLOPE=0.2

struct Rel {
  const int* src; const int* dst;
  const float* als; const float* ald;   // precomputed per-node logits [N,8]
  const float* hsrc;                    // source features [N,64]
  float* m; float* s; float* acc;       // segmax [N,8], denom [N,8], accum [N,64]
  int n_dst;
};
struct Rels { Rel r[4]; };
struct SemP { const float* p[4]; int n[4]; };

__device__ __forceinline__ void atomicMaxF(float* a, float v) {
  // init bit pattern 0xFFFFFFFF (from memset 0xFF) acts as -inf here
  if (v >= 0.0f) atomicMax((int*)a, __float_as_int(v));
  else           atomicMin((unsigned int*)a, __float_as_uint(v));
}

// K1: h = x@W^T + b ; al_k[n,head] = sum_d h[n,head,d]*att_k[head,d]
__global__ __launch_bounds__(256) void transform_kernel(
    const float* __restrict__ x, const float* __restrict__ W, const float* __restrict__ b,
    const float* __restrict__ att0, const float* __restrict__ att1,
    const float* __restrict__ att2, const float* __restrict__ att3,
    float* __restrict__ hout,
    float* __restrict__ al0, float* __restrict__ al1,
    float* __restrict__ al2, float* __restrict__ al3, int N) {
  __shared__ float Wl[64][65];   // +1 pad: lanes read Wl[c][k] conflict-free
  __shared__ float xl[4][64];
  int tid = threadIdx.x;
  for (int i = tid; i < 4096; i += 256) Wl[i>>6][i&63] = W[i];
  int nb = blockIdx.x*4;
  {
    int node = nb + (tid>>6);
    if (node < N) xl[tid>>6][tid&63] = x[(size_t)node*64 + (tid&63)];
  }
  __syncthreads();
  int nl = tid>>6, c = tid&63;
  int n = nb + nl;
  if (n >= N) return;
  float acc = b[c];
  #pragma unroll
  for (int k = 0; k < 64; ++k) acc += xl[nl][k]*Wl[c][k];
  hout[(size_t)n*64+c] = acc;
  float p0 = acc*att0[c], p1 = acc*att1[c], p2 = acc*att2[c], p3 = acc*att3[c];
  #pragma unroll
  for (int mask = 1; mask < 8; mask <<= 1) {  // reduce over d within each head's 8 lanes
    p0 += __shfl_xor(p0, mask);
    p1 += __shfl_xor(p1, mask);
    p2 += __shfl_xor(p2, mask);
    p3 += __shfl_xor(p3, mask);
  }
  int d = c&7, h = c>>3;
  if      (d == 0) al0[n*8+h] = p0;
  else if (d == 1) al1[n*8+h] = p1;
  else if (d == 2) al2[n*8+h] = p2;
  else if (d == 3) al3[n*8+h] = p3;
}

// K2: per-edge leaky(alpha) scatter-max into m[dst,h]
__global__ __launch_bounds__(256) void edge_max_kernel(Rels P) {
  Rel R = P.r[blockIdx.y];
  int e = blockIdx.x*256 + threadIdx.x;
  if (e >= NEDGES) return;
  int s = R.src[e], d = R.dst[e];
  const float4* as4 = (const float4*)R.als + (size_t)s*2;
  const float4* ad4 = (const float4*)R.ald + (size_t)d*2;
  float4 a0 = as4[0], a1 = as4[1], b0 = ad4[0], b1 = ad4[1];
  float al[8] = {a0.x+b0.x, a0.y+b0.y, a0.z+b0.z, a0.w+b0.w,
                 a1.x+b1.x, a1.y+b1.y, a1.z+b1.z, a1.w+b1.w};
  #pragma unroll
  for (int h = 0; h < 8; ++h) {
    float v = al[h]; v = v >= 0.f ? v : 0.2f*v;
    atomicMaxF(&R.m[(size_t)d*8+h], v);
  }
}

// K3: 64 lanes per edge; ex = exp(alpha - m); scatter-add denom + ex*h_src
__global__ __launch_bounds__(256) void edge_agg_kernel(Rels P) {
  Rel R = P.r[blockIdx.y];
  int t = blockIdx.x*256 + threadIdx.x;   // < E*64 = 64M, fits int
  int e = t >> 6;
  if (e >= NEDGES) return;
  int c = t & 63;
  int s = R.src[e], d = R.dst[e];
  int h = c >> 3;
  float alpha = R.als[(size_t)s*8+h] + R.ald[(size_t)d*8+h];
  alpha = alpha >= 0.f ? alpha : 0.2f*alpha;
  float ex = expf(alpha - R.m[(size_t)d*8+h]);
  if ((c&7) == 0) atomicAdd(&R.s[(size_t)d*8+h], ex);
  atomicAdd(&R.acc[(size_t)d*64+c], ex * R.hsrc[(size_t)s*64+c]);
}

// K4: out = relu(acc / (s + 1e-16)) in place
__global__ __launch_bounds__(256) void norm_relu_kernel(Rels P) {
  Rel R = P.r[blockIdx.y];
  int i = blockIdx.x*256 + threadIdx.x;
  int n_el = R.n_dst*64;
  if (i >= n_el) return;
  int n = i >> 6, h = (i>>3)&7;
  float v = R.acc[i] / (R.s[(size_t)n*8+h] + 1e-16f);
  R.acc[i] = v > 0.f ? v : 0.f;
}

// K5: semacc[mp][c] += sum_n tanh( (O[n]@kw^T + kb)[c] )
__global__ __launch_bounds__(256) void sem_stats_kernel(SemP P,
    const float* __restrict__ kw, const float* __restrict__ kb,
    float* __restrict__ semacc) {
  int mp = blockIdx.y;
  const float* O = P.p[mp]; int N = P.n[mp];
  __shared__ float Kl[64][65];
  __shared__ float xl[4][64];
  __shared__ float red[4][64];
  int tid = threadIdx.x;
  for (int i = tid; i < 4096; i += 256) Kl[i>>6][i&63] = kw[i];
  int nl = tid>>6, c = tid&63;
  float accsum = 0.f;
  for (int nb = blockIdx.x*4; nb < N; nb += gridDim.x*4) {
    __syncthreads();
    int node = nb + nl;
    xl[nl][c] = (node < N) ? O[(size_t)node*64+c] : 0.f;
    __syncthreads();
    if (node < N) {
      float y = kb[c];
      #pragma unroll
      for (int k = 0; k < 64; ++k) y += xl[nl][k]*Kl[c][k];
      accsum += tanhf(y);
    }
  }
  red[nl][c] = accsum;
  __syncthreads();
  if (tid < 64) {
    float tot = red[0][tid]+red[1][tid]+red[2][tid]+red[3][tid];
    atomicAdd(&semacc[mp*64+tid], tot);
  }
}

// K6: scores + 2x softmax(2) -> w[4]
__global__ void sem_weights_kernel(const float* __restrict__ semacc,
                                   const float* __restrict__ q,
                                   float* __restrict__ w) {
  int c = threadIdx.x; // 64 threads, one wave
  float qc = q[c];
  float sc[4];
  const float invN[4] = {1.f/NUSERS, 1.f/NUSERS, 1.f/NGAMES, 1.f/NGAMES};
  #pragma unroll
  for (int m = 0; m < 4; ++m) {
    float v = qc * semacc[m*64+c] * invN[m];
    #pragma unroll
    for (int mask = 1; mask < 64; mask <<= 1) v += __shfl_xor(v, mask);
    sc[m] = v;
  }
  if (c == 0) {
    float m0 = fmaxf(sc[0], sc[1]);
    float e0 = expf(sc[0]-m0), e1 = expf(sc[1]-m0);
    w[0] = e0/(e0+e1); w[1] = e1/(e0+e1);
    float m1 = fmaxf(sc[2], sc[3]);
    float e2 = expf(sc[2]-m1), e3 = expf(sc[3]-m1);
    w[2] = e2/(e2+e3); w[3] = e3/(e2+e3);
  }
}

// K7: out = w0*plays + w1*rec  (in place over d_out)
__global__ __launch_bounds__(256) void combine_kernel(
    float* __restrict__ out_u, const float* __restrict__ rec_u,
    float* __restrict__ out_g, const float* __restrict__ rec_g,
    const float* __restrict__ w) {
  int i = blockIdx.x*256 + threadIdx.x;
  if (blockIdx.y == 0) {
    if (i < NUSERS*64) out_u[i] = w[0]*out_u[i] + w[1]*rec_u[i];
  } else {
    if (i < NGAMES*64) out_g[i] = w[2]*out_g[i] + w[3]*rec_g[i];
  }
}

extern "C" void kernel_launch(void* const* d_in, const int* in_sizes, int n_in,
                              void* d_out_v, int out_size, void* d_ws, size_t ws_size,
                              hipStream_t stream) {
  const float* x_user     = (const float*)d_in[0];
  const float* x_game     = (const float*)d_in[1];
  const int*   plays_src  = (const int*)d_in[2];
  const int*   plays_dst  = (const int*)d_in[3];
  const int*   rec_src    = (const int*)d_in[4];
  const int*   rec_dst    = (const int*)d_in[5];
  const float* W_user     = (const float*)d_in[6];
  const float* b_user     = (const float*)d_in[7];
  const float* W_game     = (const float*)d_in[8];
  const float* b_game     = (const float*)d_in[9];
  const float* att_src_pg = (const float*)d_in[10];
  const float* att_dst_pg = (const float*)d_in[11];
  const float* att_src_rg = (const float*)d_in[12];
  const float* att_dst_rg = (const float*)d_in[13];
  const float* att_src_pu = (const float*)d_in[14];
  const float* att_dst_pu = (const float*)d_in[15];
  const float* att_src_ru = (const float*)d_in[16];
  const float* att_dst_ru = (const float*)d_in[17];
  const float* k_lin_w    = (const float*)d_in[18];
  const float* k_lin_b    = (const float*)d_in[19];
  const float* q          = (const float*)d_in[20];
  float* out = (float*)d_out_v;
  float* ws  = (float*)d_ws;

  // ---- workspace layout (floats); total ~28.8M floats = ~115.2 MB ----
  size_t o = 0;
  float* h_u  = ws + o; o += (size_t)NUSERS*64;
  float* h_g  = ws + o; o += (size_t)NGAMES*64;
  float* alU0 = ws + o; o += (size_t)NUSERS*8;   // att_src_pg
  float* alU1 = ws + o; o += (size_t)NUSERS*8;   // att_src_rg
  float* alU2 = ws + o; o += (size_t)NUSERS*8;   // att_dst_pu
  float* alU3 = ws + o; o += (size_t)NUSERS*8;   // att_dst_ru
  float* alG0 = ws + o; o += (size_t)NGAMES*8;   // att_dst_pg
  float* alG1 = ws + o; o += (size_t)NGAMES*8;   // att_dst_rg
  float* alG2 = ws + o; o += (size_t)NGAMES*8;   // att_src_pu
  float* alG3 = ws + o; o += (size_t)NGAMES*8;   // att_src_ru
  size_t zb = o;                                  // zero-region begin
  float* s0   = ws + o; o += (size_t)NGAMES*8;
  float* s1   = ws + o; o += (size_t)NGAMES*8;
  float* s2   = ws + o; o += (size_t)NUSERS*8;
  float* s3   = ws + o; o += (size_t)NUSERS*8;
  float* acc1 = ws + o; o += (size_t)NGAMES*64;  // og_rec accum
  float* acc3 = ws + o; o += (size_t)NUSERS*64;  // ou_rec accum
  float* semacc = ws + o; o += 256;
  float* wbuf   = ws + o; o += 4;
  size_t ze = o;                                  // zero-region end
  float* m0 = ws + o; o += (size_t)NGAMES*8;
  float* m1 = ws + o; o += (size_t)NGAMES*8;
  float* m2 = ws + o; o += (size_t)NUSERS*8;
  float* m3 = ws + o; o += (size_t)NUSERS*8;

  float* out_u = out;                       // ou_plays accum -> user region
  float* out_g = out + (size_t)NUSERS*64;   // og_plays accum -> game region

  hipMemsetAsync(ws + zb, 0,   (ze - zb)*sizeof(float), stream);
  hipMemsetAsync(m0, 0xFF, (size_t)(NGAMES*16 + NUSERS*16)*sizeof(float), stream);
  hipMemsetAsync(out, 0,  (size_t)(NUSERS+NGAMES)*64*sizeof(float), stream);

  transform_kernel<<<dim3(NUSERS/4), 256, 0, stream>>>(x_user, W_user, b_user,
      att_src_pg, att_src_rg, att_dst_pu, att_dst_ru,
      h_u, alU0, alU1, alU2, alU3, NUSERS);
  transform_kernel<<<dim3(NGAMES/4), 256, 0, stream>>>(x_game, W_game, b_game,
      att_dst_pg, att_dst_rg, att_src_pu, att_src_ru,
      h_g, alG0, alG1, alG2, alG3, NGAMES);

  Rels P;
  P.r[0] = {plays_src, plays_dst, alU0, alG0, h_u, m0, s0, out_g, NGAMES}; // og_plays
  P.r[1] = {rec_src,   rec_dst,   alU1, alG1, h_u, m1, s1, acc1,  NGAMES}; // og_rec
  P.r[2] = {plays_dst, plays_src, alG2, alU2, h_g, m2, s2, out_u, NUSERS}; // ou_plays
  P.r[3] = {rec_dst,   rec_src,   alG3, alU3, h_g, m3, s3, acc3,  NUSERS}; // ou_rec

  edge_max_kernel<<<dim3((NEDGES+255)/256, 4), 256, 0, stream>>>(P);
  edge_agg_kernel<<<dim3(NEDGES/4, 4), 256, 0, stream>>>(P);
  norm_relu_kernel<<<dim3((NUSERS*64+255)/256, 4), 256, 0, stream>>>(P);

  SemP S;
  S.p[0] = out_u; S.p[1] = acc3; S.p[2] = out_g; S.p[3] = acc1;
  S.n[0] = NUSERS; S.n[1] = NUSERS; S.n[2] = NGAMES; S.n[3] = NGAMES;
  sem_stats_kernel<<<dim3(256,4), 256, 0, stream>>>(S, k_lin_w, k_lin_b, semacc);
  sem_weights_kernel<<<1, 64, 0, stream>>>(semacc, q, wbuf);
  combine_kernel<<<dim3((NUSERS*64+255)/256, 2), 256, 0, stream>>>(out_u, acc3, out_g, acc1, wbuf);
}

// Round 3
// 1198.133 us; speedup vs baseline: 2.3586x; 2.3586x over previous
//
#include <hip/hip_runtime.h>

#define NUSERS 100000
#define NGAMES 50000
#define NEDGES 1000000
#define NT     300000   // concatenated dst-counter space: 2*NGAMES + 2*NUSERS
#define NT4    75000    // NT/4
#define SCAN_B 293      // ceil(NT4/256)
// C=64, H=8, D=8, NEG_SLOPE=0.2

struct EdgeRel { const int* dst; const int* src; int base; };
struct ERels { EdgeRel r[4]; };
struct AggRel { const float* als; const float* ald; const float* hsrc;
                float* outp; int base; int n_dst; };
struct ARels { AggRel r[4]; };
struct SemP { const float* p[4]; int n[4]; };

// K1: h = x@W^T + b ; al_k[n,head] = sum_d h[n,head,d]*att_k[head,d]
__global__ __launch_bounds__(256) void transform_kernel(
    const float* __restrict__ x, const float* __restrict__ W, const float* __restrict__ b,
    const float* __restrict__ att0, const float* __restrict__ att1,
    const float* __restrict__ att2, const float* __restrict__ att3,
    float* __restrict__ hout,
    float* __restrict__ al0, float* __restrict__ al1,
    float* __restrict__ al2, float* __restrict__ al3, int N) {
  __shared__ float Wl[64][65];   // +1 pad: lanes read Wl[c][k] conflict-free
  __shared__ float xl[4][64];
  int tid = threadIdx.x;
  for (int i = tid; i < 4096; i += 256) Wl[i>>6][i&63] = W[i];
  int nb = blockIdx.x*4;
  {
    int node = nb + (tid>>6);
    if (node < N) xl[tid>>6][tid&63] = x[(size_t)node*64 + (tid&63)];
  }
  __syncthreads();
  int nl = tid>>6, c = tid&63;
  int n = nb + nl;
  if (n >= N) return;
  float acc = b[c];
  #pragma unroll
  for (int k = 0; k < 64; ++k) acc += xl[nl][k]*Wl[c][k];
  hout[(size_t)n*64+c] = acc;
  float p0 = acc*att0[c], p1 = acc*att1[c], p2 = acc*att2[c], p3 = acc*att3[c];
  #pragma unroll
  for (int mask = 1; mask < 8; mask <<= 1) {  // reduce over d within each head's 8 lanes
    p0 += __shfl_xor(p0, mask);
    p1 += __shfl_xor(p1, mask);
    p2 += __shfl_xor(p2, mask);
    p3 += __shfl_xor(p3, mask);
  }
  int d = c&7, h = c>>3;
  if      (d == 0) al0[n*8+h] = p0;
  else if (d == 1) al1[n*8+h] = p1;
  else if (d == 2) al2[n*8+h] = p2;
  else if (d == 3) al3[n*8+h] = p3;
}

// K2: degree histogram over concatenated counter space
__global__ __launch_bounds__(256) void hist_kernel(ERels P, int* __restrict__ deg) {
  EdgeRel R = P.r[blockIdx.y];
  int e = blockIdx.x*256 + threadIdx.x;
  if (e >= NEDGES) return;
  atomicAdd(&deg[R.base + R.dst[e]], 1);
}

// K3a: per-block (1024-elem) sums
__global__ __launch_bounds__(256) void scan_blocksum(const int* __restrict__ deg,
                                                     int* __restrict__ bsum) {
  __shared__ int red[256];
  int t = threadIdx.x;
  int i4 = blockIdx.x*256 + t;
  int4 v = (i4 < NT4) ? ((const int4*)deg)[i4] : int4{0,0,0,0};
  red[t] = v.x+v.y+v.z+v.w;
  __syncthreads();
  for (int off = 128; off > 0; off >>= 1) {
    if (t < off) red[t] += red[t+off];
    __syncthreads();
  }
  if (t == 0) bsum[blockIdx.x] = red[0];
}

// K3b: exclusive scan of block sums (single block)
__global__ __launch_bounds__(512) void scan_top(const int* __restrict__ bsum,
                                                int* __restrict__ boff) {
  __shared__ int sc[512];
  int t = threadIdx.x;
  int v = (t < SCAN_B) ? bsum[t] : 0;
  sc[t] = v;
  __syncthreads();
  for (int off = 1; off < 512; off <<= 1) {
    int add = (t >= off) ? sc[t-off] : 0;
    __syncthreads();
    sc[t] += add;
    __syncthreads();
  }
  if (t < SCAN_B) boff[t] = sc[t] - v;
}

// K3c: final exclusive scan -> start[] and cursor[] (two copies)
__global__ __launch_bounds__(256) void scan_final(const int* __restrict__ deg,
    const int* __restrict__ boff, int* __restrict__ start, int* __restrict__ cursor) {
  __shared__ int sc[256];
  int t = threadIdx.x;
  int i4 = blockIdx.x*256 + t;
  int4 v = (i4 < NT4) ? ((const int4*)deg)[i4] : int4{0,0,0,0};
  int s01 = v.x + v.y;
  int sum = s01 + v.z + v.w;
  sc[t] = sum;
  __syncthreads();
  for (int off = 1; off < 256; off <<= 1) {
    int add = (t >= off) ? sc[t-off] : 0;
    __syncthreads();
    sc[t] += add;
    __syncthreads();
  }
  int excl = sc[t] - sum + boff[blockIdx.x];
  if (i4 < NT4) {
    int4 st;
    st.x = excl;
    st.y = excl + v.x;
    st.z = excl + s01;
    st.w = excl + s01 + v.z;
    ((int4*)start)[i4] = st;
    ((int4*)cursor)[i4] = st;
  }
}

// K4: scatter src index into dst-grouped slots (atomic ticket)
__global__ __launch_bounds__(256) void scatter_kernel(ERels P, int* __restrict__ cursor,
                                                      int* __restrict__ src_sorted) {
  EdgeRel R = P.r[blockIdx.y];
  int e = blockIdx.x*256 + threadIdx.x;
  if (e >= NEDGES) return;
  int slot = atomicAdd(&cursor[R.base + R.dst[e]], 1);
  src_sorted[slot] = R.src[e];
}

// K5: one wave per (dst node, relation): register-accumulated softmax-agg,
//     denominator + normalize + relu fused. Zero atomics.
//     Src indices prefetched 64-wide per chunk, broadcast via shfl so the
//     inner-loop gathers have no load->load dependency.
__global__ __launch_bounds__(256) void agg_kernel(ARels P,
    const int* __restrict__ csr_start, const int* __restrict__ deg,
    const int* __restrict__ src_sorted) {
  AggRel R = P.r[blockIdx.y];
  int lane = threadIdx.x & 63, wid = threadIdx.x >> 6;
  int n = blockIdx.x*4 + wid;
  if (n >= R.n_dst) return;
  int h = lane >> 3;
  float aldv = R.ald[(size_t)n*8 + h];
  int start = csr_start[R.base + n];
  int dcount = deg[R.base + n];
  float acc = 0.f, den = 0.f;
  for (int j0 = 0; j0 < dcount; j0 += 64) {
    int idx = j0 + lane;
    int mysrc = (idx < dcount) ? src_sorted[start + idx] : 0;
    int cnt = dcount - j0; if (cnt > 64) cnt = 64;
    for (int jj = 0; jj < cnt; ++jj) {
      int s = __shfl(mysrc, jj);
      float a = R.als[(size_t)s*8 + h] + aldv;
      a = a >= 0.f ? a : 0.2f*a;
      float ex = __expf(a);    // no max-subtraction: softmax is shift-invariant
      den += ex;
      acc += ex * R.hsrc[(size_t)s*64 + lane];
    }
  }
  float v = acc / (den + 1e-16f);
  R.outp[(size_t)n*64 + lane] = v > 0.f ? v : 0.f;
}

// K6: semacc[mp][c] += sum_n tanh( (O[n]@kw^T + kb)[c] )
__global__ __launch_bounds__(256) void sem_stats_kernel(SemP P,
    const float* __restrict__ kw, const float* __restrict__ kb,
    float* __restrict__ semacc) {
  int mp = blockIdx.y;
  const float* O = P.p[mp]; int N = P.n[mp];
  __shared__ float Kl[64][65];
  __shared__ float xl[4][64];
  __shared__ float red[4][64];
  int tid = threadIdx.x;
  for (int i = tid; i < 4096; i += 256) Kl[i>>6][i&63] = kw[i];
  int nl = tid>>6, c = tid&63;
  float accsum = 0.f;
  for (int nb = blockIdx.x*4; nb < N; nb += gridDim.x*4) {
    __syncthreads();
    int node = nb + nl;
    xl[nl][c] = (node < N) ? O[(size_t)node*64+c] : 0.f;
    __syncthreads();
    if (node < N) {
      float y = kb[c];
      #pragma unroll
      for (int k = 0; k < 64; ++k) y += xl[nl][k]*Kl[c][k];
      accsum += tanhf(y);
    }
  }
  red[nl][c] = accsum;
  __syncthreads();
  if (tid < 64) {
    float tot = red[0][tid]+red[1][tid]+red[2][tid]+red[3][tid];
    atomicAdd(&semacc[mp*64+tid], tot);
  }
}

// K7: scores + 2x softmax(2) -> w[4]
__global__ void sem_weights_kernel(const float* __restrict__ semacc,
                                   const float* __restrict__ q,
                                   float* __restrict__ w) {
  int c = threadIdx.x; // 64 threads, one wave
  float qc = q[c];
  float sc[4];
  const float invN[4] = {1.f/NUSERS, 1.f/NUSERS, 1.f/NGAMES, 1.f/NGAMES};
  #pragma unroll
  for (int m = 0; m < 4; ++m) {
    float v = qc * semacc[m*64+c] * invN[m];
    #pragma unroll
    for (int mask = 1; mask < 64; mask <<= 1) v += __shfl_xor(v, mask);
    sc[m] = v;
  }
  if (c == 0) {
    float m0 = fmaxf(sc[0], sc[1]);
    float e0 = expf(sc[0]-m0), e1 = expf(sc[1]-m0);
    w[0] = e0/(e0+e1); w[1] = e1/(e0+e1);
    float m1 = fmaxf(sc[2], sc[3]);
    float e2 = expf(sc[2]-m1), e3 = expf(sc[3]-m1);
    w[2] = e2/(e2+e3); w[3] = e3/(e2+e3);
  }
}

// K8: out = w0*plays + w1*rec  (in place over d_out)
__global__ __launch_bounds__(256) void combine_kernel(
    float* __restrict__ out_u, const float* __restrict__ rec_u,
    float* __restrict__ out_g, const float* __restrict__ rec_g,
    const float* __restrict__ w) {
  int i = blockIdx.x*256 + threadIdx.x;
  if (blockIdx.y == 0) {
    if (i < NUSERS*64) out_u[i] = w[0]*out_u[i] + w[1]*rec_u[i];
  } else {
    if (i < NGAMES*64) out_g[i] = w[2]*out_g[i] + w[3]*rec_g[i];
  }
}

extern "C" void kernel_launch(void* const* d_in, const int* in_sizes, int n_in,
                              void* d_out_v, int out_size, void* d_ws, size_t ws_size,
                              hipStream_t stream) {
  const float* x_user     = (const float*)d_in[0];
  const float* x_game     = (const float*)d_in[1];
  const int*   plays_src  = (const int*)d_in[2];
  const int*   plays_dst  = (const int*)d_in[3];
  const int*   rec_src    = (const int*)d_in[4];
  const int*   rec_dst    = (const int*)d_in[5];
  const float* W_user     = (const float*)d_in[6];
  const float* b_user     = (const float*)d_in[7];
  const float* W_game     = (const float*)d_in[8];
  const float* b_game     = (const float*)d_in[9];
  const float* att_src_pg = (const float*)d_in[10];
  const float* att_dst_pg = (const float*)d_in[11];
  const float* att_src_rg = (const float*)d_in[12];
  const float* att_dst_rg = (const float*)d_in[13];
  const float* att_src_pu = (const float*)d_in[14];
  const float* att_dst_pu = (const float*)d_in[15];
  const float* att_src_ru = (const float*)d_in[16];
  const float* att_dst_ru = (const float*)d_in[17];
  const float* k_lin_w    = (const float*)d_in[18];
  const float* k_lin_b    = (const float*)d_in[19];
  const float* q          = (const float*)d_in[20];
  float* out = (float*)d_out_v;
  float* ws  = (float*)d_ws;

  // ---- workspace layout (all region sizes multiple of 16 B) ----
  size_t o = 0;
  float* h_u  = ws + o; o += (size_t)NUSERS*64;
  float* h_g  = ws + o; o += (size_t)NGAMES*64;
  float* alU0 = ws + o; o += (size_t)NUSERS*8;   // att_src_pg
  float* alU1 = ws + o; o += (size_t)NUSERS*8;   // att_src_rg
  float* alU2 = ws + o; o += (size_t)NUSERS*8;   // att_dst_pu
  float* alU3 = ws + o; o += (size_t)NUSERS*8;   // att_dst_ru
  float* alG0 = ws + o; o += (size_t)NGAMES*8;   // att_dst_pg
  float* alG1 = ws + o; o += (size_t)NGAMES*8;   // att_dst_rg
  float* alG2 = ws + o; o += (size_t)NGAMES*8;   // att_src_pu
  float* alG3 = ws + o; o += (size_t)NGAMES*8;   // att_src_ru
  float* acc1 = ws + o; o += (size_t)NGAMES*64;  // og_rec result
  float* acc3 = ws + o; o += (size_t)NUSERS*64;  // ou_rec result
  float* semacc = ws + o; o += 256;
  float* wbuf   = ws + o; o += 4;
  o = (o + 3) & ~(size_t)3;
  int* deg        = (int*)(ws + o); o += NT;       // degree counters (zeroed)
  int* csr_start  = (int*)(ws + o); o += NT;
  int* cursor     = (int*)(ws + o); o += NT;
  int* bsum       = (int*)(ws + o); o += 512;
  int* boff       = (int*)(ws + o); o += 512;
  int* src_sorted = (int*)(ws + o); o += (size_t)4*NEDGES;

  float* out_u = out;                       // ou_plays result -> user region
  float* out_g = out + (size_t)NUSERS*64;   // og_plays result -> game region

  hipMemsetAsync(deg, 0, (size_t)NT*sizeof(int), stream);
  hipMemsetAsync(semacc, 0, 260*sizeof(float), stream);

  transform_kernel<<<dim3(NUSERS/4), 256, 0, stream>>>(x_user, W_user, b_user,
      att_src_pg, att_src_rg, att_dst_pu, att_dst_ru,
      h_u, alU0, alU1, alU2, alU3, NUSERS);
  transform_kernel<<<dim3(NGAMES/4), 256, 0, stream>>>(x_game, W_game, b_game,
      att_dst_pg, att_dst_rg, att_src_pu, att_src_ru,
      h_g, alG0, alG1, alG2, alG3, NGAMES);

  // relation -> (aggregation dst, feature src, counter-space base)
  ERels EP;
  EP.r[0] = {plays_dst, plays_src, 0};            // og_plays (dst=games)
  EP.r[1] = {rec_dst,   rec_src,   NGAMES};       // og_rec   (dst=games)
  EP.r[2] = {plays_src, plays_dst, 2*NGAMES};     // ou_plays (dst=users)
  EP.r[3] = {rec_src,   rec_dst,   2*NGAMES+NUSERS}; // ou_rec (dst=users)

  hist_kernel<<<dim3((NEDGES+255)/256, 4), 256, 0, stream>>>(EP, deg);
  scan_blocksum<<<dim3(SCAN_B), 256, 0, stream>>>(deg, bsum);
  scan_top<<<dim3(1), 512, 0, stream>>>(bsum, boff);
  scan_final<<<dim3(SCAN_B), 256, 0, stream>>>(deg, boff, csr_start, cursor);
  scatter_kernel<<<dim3((NEDGES+255)/256, 4), 256, 0, stream>>>(EP, cursor, src_sorted);

  ARels AP;
  AP.r[0] = {alU0, alG0, h_u, out_g, 0,                 NGAMES};
  AP.r[1] = {alU1, alG1, h_u, acc1,  NGAMES,            NGAMES};
  AP.r[2] = {alG2, alU2, h_g, out_u, 2*NGAMES,          NUSERS};
  AP.r[3] = {alG3, alU3, h_g, acc3,  2*NGAMES+NUSERS,   NUSERS};

  agg_kernel<<<dim3((NUSERS+3)/4, 4), 256, 0, stream>>>(AP, csr_start, deg, src_sorted);

  SemP S;
  S.p[0] = out_u; S.p[1] = acc3; S.p[2] = out_g; S.p[3] = acc1;
  S.n[0] = NUSERS; S.n[1] = NUSERS; S.n[2] = NGAMES; S.n[3] = NGAMES;
  sem_stats_kernel<<<dim3(256,4), 256, 0, stream>>>(S, k_lin_w, k_lin_b, semacc);
  sem_weights_kernel<<<1, 64, 0, stream>>>(semacc, q, wbuf);
  combine_kernel<<<dim3((NUSERS*64+255)/256, 2), 256, 0, stream>>>(out_u, acc3, out_g, acc1, wbuf);
}